// Round 15
// baseline (84.996 us; speedup 1.0000x reference)
//
#include <hip/hip_runtime.h>
#include <math.h>

#define NCL  27
#define CCH  512
#define HWPX 9216            // 96*96
#define NB   16
#define NPIX (NB * HWPX)     // 147456
#define EPSN 1e-12f
#define NCHK 32              // K chunks of 16

typedef short        short8 __attribute__((ext_vector_type(8)));
typedef float        f32x16 __attribute__((ext_vector_type(16)));

// RNE bf16 conversion for the (one-time) cluster prep
__device__ __forceinline__ unsigned short f2bf(float f) {
    unsigned u = __float_as_uint(f);
    return (unsigned short)((u + 0x7fffu + ((u >> 16) & 1u)) >> 16);
}
__device__ __forceinline__ float bf2f(unsigned short h) {
    return __uint_as_float(((unsigned)h) << 16);
}

// fire-and-forget global->LDS DMA: per-lane global src, LDS dest = wave-uniform
// base + lane*16 (linear)
__device__ __forceinline__ void gload_lds16(const float* g, float* lds) {
    __builtin_amdgcn_global_load_lds(
        (const __attribute__((address_space(1))) unsigned int*)g,
        (__attribute__((address_space(3))) unsigned int*)lds,
        16, 0, 0);
}

// ---------------------------------------------------------------------------
// k0: normalize clusters (fp32), split into bf16 hi/lo (RNE), write
// A-fragments in 32x32x16 MFMA lane layout:
//   A[row=m][k] -> clA[chunk][lane][j], lane = m + 32*half, k = chunk*16+8*half+j
// rows 27..31 zero-pad. Also zero the 32 loss slots. grid = 32 x 64.
// ---------------------------------------------------------------------------
__global__ __launch_bounds__(64) void k0_prep(const float* __restrict__ cl,
                                              unsigned short* __restrict__ clAhi,
                                              unsigned short* __restrict__ clAlo,
                                              float* __restrict__ loss_acc) {
    const int n = blockIdx.x;            // A row 0..31
    const int t = threadIdx.x;
    float inv = 0.f;
    if (n < NCL) {
        const float* row = cl + n * CCH;
        float ss = 0.f;
#pragma unroll
        for (int i = 0; i < CCH / 64; ++i) {
            float v = row[i * 64 + t];
            ss = fmaf(v, v, ss);
        }
#pragma unroll
        for (int off = 32; off > 0; off >>= 1)
            ss += __shfl_xor(ss, off, 64);
        inv = 1.0f / fmaxf(sqrtf(ss), EPSN);
    }
    const int chunk = t >> 1;
    const int half  = t & 1;
    const int lane  = n + 32 * half;
    const size_t base = ((size_t)chunk * 64 + lane) * 8;
#pragma unroll
    for (int j = 0; j < 8; ++j) {
        const int k = chunk * 16 + 8 * half + j;
        float v = (n < NCL) ? cl[n * CCH + k] * inv : 0.f;
        unsigned short h = f2bf(v);
        float lo = v - bf2f(h);
        clAhi[base + j] = h;
        clAlo[base + j] = f2bf(lo);
    }
    if (n == 0 && t < 32) loss_acc[t * 32] = 0.f;   // 32 line-padded slots
}

// per-chunk compute: 8 LDS reads (2-way bank alias = free), truncation hi/lo
// split (shift+or, SDWA-foldable), 3 MFMAs (ah*bh + al*bh + ah*bl ~= fp32)
__device__ __forceinline__ void compute_chunk(const float (*buf)[32],
                                              short8 ah, short8 al,
                                              f32x16& acc, float& ss,
                                              int col, int half) {
    float xv[8];
#pragma unroll
    for (int j = 0; j < 8; ++j)
        xv[j] = buf[8 * half + j][col];

    unsigned hb[8], ub[8], lb[8];
#pragma unroll
    for (int j = 0; j < 8; ++j) {
        ss = fmaf(xv[j], xv[j], ss);               // exact fp32 self-norm
        ub[j] = __float_as_uint(xv[j]);
        hb[j] = ub[j] & 0xFFFF0000u;               // truncated bf16 (f32 bits)
        lb[j] = __float_as_uint(xv[j] - __uint_as_float(hb[j]));  // exact lo
    }
    unsigned bhp[4], blp[4];
#pragma unroll
    for (int i = 0; i < 4; ++i) {
        bhp[i] = (ub[2 * i] >> 16) | hb[2 * i + 1];
        blp[i] = (lb[2 * i] >> 16) | (lb[2 * i + 1] & 0xFFFF0000u);
    }
    short8 bh, bl;
#pragma unroll
    for (int i = 0; i < 4; ++i) {
        bh[2 * i]     = (short)(bhp[i] & 0xFFFFu);
        bh[2 * i + 1] = (short)(bhp[i] >> 16);
        bl[2 * i]     = (short)(blp[i] & 0xFFFFu);
        bl[2 * i + 1] = (short)(blp[i] >> 16);
    }
    acc = __builtin_amdgcn_mfma_f32_32x32x16_bf16(ah, bh, acc, 0, 0, 0);
    acc = __builtin_amdgcn_mfma_f32_32x32x16_bf16(al, bh, acc, 0, 0, 0);
    acc = __builtin_amdgcn_mfma_f32_32x32x16_bf16(ah, bl, acc, 0, 0, 0);
}

// ---------------------------------------------------------------------------
// k1: MFMA + wave-private global_load_lds double-buffer, ZERO barriers,
//  EXPLICIT counted vmcnt (T4). 1-wave blocks (grid 4608, ~18 waves/CU).
//  Per chunk the wave stages all 16ch x its 32px (2x 1KB glds; lane l ->
//  ch (l>>3), px (l&7)*4 -> LDS float 4l: layouts coincide) into xtA/xtB.
//  RACE FIX vs r14: the DMA->ds_read dep has no register chain, so the
//  compiler emits NO wait (r14: absmax 0.10). We insert
//  `s_waitcnt vmcnt(4)` after STAGE(t+1): >=4 vmem ops (2 A-frags +
//  2 glds) always sit between STAGE(t) and the wait (asm memory clobbers
//  pin both classes), and vmem retires in-order => <=4 outstanding proves
//  STAGE(t) landed. Last chunk peeled with vmcnt(0).
//  C: col=lane&31=pixel, row=(r&3)+8*(r>>2)+4*half; valid rows<27
//  (r<12 always, r=12..14 half 0; r==15/half0 is pad row 27).
//  [ledger: r9 unroll4 +7us, r10 fence +210us, r11 perm +5.5us,
//   r13 barrier-staged 68.6us, r14 no-wait RACED]
// ---------------------------------------------------------------------------
__global__ __launch_bounds__(64) void k1_main(const float* __restrict__ x,
                                              const unsigned short* __restrict__ clAhi,
                                              const unsigned short* __restrict__ clAlo,
                                              const float* __restrict__ alpha_p,
                                              float* __restrict__ out,
                                              float* __restrict__ loss_acc) {
    __shared__ float xtA[16][32];                 // 2 KB
    __shared__ float xtB[16][32];                 // 2 KB

    const int l    = threadIdx.x;
    const int px0  = blockIdx.x * 32;
    const int b    = px0 / HWPX;                  // uniform (32 | 9216)
    const int hw0  = px0 - b * HWPX;
    const int col  = l & 31;                      // pixel within tile
    const int half = l >> 5;                      // k-half

    // staging source: lane l loads 16B = ch (l>>3), pixels hw0+(l&7)*4..+3
    const float* xsrc = x + ((size_t)b * CCH + (l >> 3)) * HWPX
                          + hw0 + (l & 7) * 4;
    const unsigned short* pAh = clAhi + (size_t)l * 8;
    const unsigned short* pAl = clAlo + (size_t)l * 8;

#define STAGE(tc, dst)                                                    \
    {                                                                     \
        gload_lds16(xsrc + (size_t)(tc) * 16 * HWPX,       &dst[0][0]);   \
        gload_lds16(xsrc + ((size_t)(tc) * 16 + 8) * HWPX, &dst[8][0]);   \
    }

    f32x16 acc = {0.f, 0.f, 0.f, 0.f, 0.f, 0.f, 0.f, 0.f,
                  0.f, 0.f, 0.f, 0.f, 0.f, 0.f, 0.f, 0.f};
    float ss = 0.f;

    STAGE(0, xtA);

    for (int t = 0; t < NCHK - 2; t += 2) {
        // even: A-frags(t), prefetch t+1 -> xtB, counted wait, compute xtA
        short8 ah0 = *(const short8*)(pAh + (size_t)t * 512);
        short8 al0 = *(const short8*)(pAl + (size_t)t * 512);
        STAGE(t + 1, xtB);
        asm volatile("s_waitcnt vmcnt(4)" ::: "memory");   // STAGE(t) landed
        compute_chunk(xtA, ah0, al0, acc, ss, col, half);

        // odd: A-frags(t+1), prefetch t+2 -> xtA, counted wait, compute xtB
        short8 ah1 = *(const short8*)(pAh + (size_t)(t + 1) * 512);
        short8 al1 = *(const short8*)(pAl + (size_t)(t + 1) * 512);
        STAGE(t + 2, xtA);
        asm volatile("s_waitcnt vmcnt(4)" ::: "memory");   // STAGE(t+1) landed
        compute_chunk(xtB, ah1, al1, acc, ss, col, half);
    }
    {   // peeled last pair (t = 30, 31)
        short8 ah0 = *(const short8*)(pAh + (size_t)30 * 512);
        short8 al0 = *(const short8*)(pAl + (size_t)30 * 512);
        STAGE(31, xtB);
        asm volatile("s_waitcnt vmcnt(4)" ::: "memory");   // STAGE(30) landed
        compute_chunk(xtA, ah0, al0, acc, ss, col, half);

        short8 ah1 = *(const short8*)(pAh + (size_t)31 * 512);
        short8 al1 = *(const short8*)(pAl + (size_t)31 * 512);
        asm volatile("s_waitcnt vmcnt(0)" ::: "memory");   // full drain (once)
        compute_chunk(xtB, ah1, al1, acc, ss, col, half);
    }
#undef STAGE

    // ---- epilogue (identical to r8) ----
    ss += __shfl_xor(ss, 32, 64);                 // combine k-halves of pixel
    const float inv_x = 1.0f / fmaxf(sqrtf(ss), EPSN);
    const float alpha = alpha_p[0];

    float ip[16], ex[16];
#pragma unroll
    for (int r = 0; r < 16; ++r) {
        ip[r] = acc[r] * inv_x;                   // cosine (cl-norm folded in A)
        ex[r] = ip[r] * alpha;
    }

    // valid (row<27): r<12 always; r in 12..14 only on half 0
    float m = -1e30f;
#pragma unroll
    for (int r = 0; r < 12; ++r) m = fmaxf(m, ex[r]);
    if (half == 0) {
#pragma unroll
        for (int r = 12; r < 15; ++r) m = fmaxf(m, ex[r]);
    }
    m = fmaxf(m, __shfl_xor(m, 32, 64));          // max over all 27

    float sum = 0.f;
#pragma unroll
    for (int r = 0; r < 12; ++r) {
        ex[r] = __expf(ex[r] - m);
        sum += ex[r];
    }
#pragma unroll
    for (int r = 12; r < 16; ++r) {
        float e = (half == 0 && r < 15) ? __expf(ex[r] - m) : 0.f;
        ex[r] = e;
        sum += e;
    }
    sum += __shfl_xor(sum, 32, 64);               // denom over all 27
    const float inv_sum = 1.0f / sum;

    float lterm = 0.f;
    float* ob = out + 1 + (size_t)b * (NCL * HWPX) + hw0 + col;
#pragma unroll
    for (int r = 0; r < 16; ++r) {
        const int row = (r & 3) + 8 * (r >> 2) + 4 * half;
        if (r < 12 || (half == 0 && r < 15)) {    // row < 27 only
            float pr = ex[r] * inv_sum;
            ob[(size_t)row * HWPX] = pr;          // coalesced 128B segments
            lterm = fmaf(pr, ip[r], lterm);
        }
    }

    // per-(pixel,half) partials; 64-lane sum counts each (pixel,row) once
#pragma unroll
    for (int off = 32; off > 0; off >>= 1)
        lterm += __shfl_xor(lterm, off, 64);
    if (l == 0)
        atomicAdd(&loss_acc[(blockIdx.x & 31) * 32], lterm);   // 32-way spread
}

// ---------------------------------------------------------------------------
// k2: finalize loss (sum the 32 slots)
// ---------------------------------------------------------------------------
__global__ void k2_fin(const float* __restrict__ loss_acc,
                       float* __restrict__ out) {
    float s = 0.f;
#pragma unroll
    for (int i = 0; i < 32; ++i) s += loss_acc[i * 32];
    out[0] = -s * (1.0f / (float)NPIX);
}

extern "C" void kernel_launch(void* const* d_in, const int* in_sizes, int n_in,
                              void* d_out, int out_size, void* d_ws, size_t ws_size,
                              hipStream_t stream) {
    const float* x     = (const float*)d_in[0];
    const float* cl    = (const float*)d_in[1];
    const float* alpha = (const float*)d_in[2];
    float* out = (float*)d_out;

    float*          loss_acc = (float*)d_ws;                       // 32 slots x 128B
    unsigned short* clAhi    = (unsigned short*)((char*)d_ws + 4096);
    unsigned short* clAlo    = clAhi + 32 * 64 * 8;                // +32KB

    hipLaunchKernelGGL(k0_prep, dim3(32), dim3(64), 0, stream,
                       cl, clAhi, clAlo, loss_acc);
    hipLaunchKernelGGL(k1_main, dim3(NPIX / 32), dim3(64), 0, stream,
                       x, clAhi, clAlo, alpha, out, loss_acc);
    hipLaunchKernelGGL(k2_fin, dim3(1), dim3(1), 0, stream, loss_acc, out);
}

// Round 16
// 68.244 us; speedup vs baseline: 1.2455x; 1.2455x over previous
//
#include <hip/hip_runtime.h>
#include <math.h>

#define NCL  27
#define CCH  512
#define HWPX 9216            // 96*96
#define NB   16
#define NPIX (NB * HWPX)     // 147456
#define EPSN 1e-12f
#define NCHK 32              // K chunks of 16
#define PXT  128             // pixels per block (4 waves x 32-px MFMA tiles)

typedef short        short8 __attribute__((ext_vector_type(8)));
typedef float        f32x16 __attribute__((ext_vector_type(16)));

// RNE bf16 conversion for the (one-time) cluster prep
__device__ __forceinline__ unsigned short f2bf(float f) {
    unsigned u = __float_as_uint(f);
    return (unsigned short)((u + 0x7fffu + ((u >> 16) & 1u)) >> 16);
}
__device__ __forceinline__ float bf2f(unsigned short h) {
    return __uint_as_float(((unsigned)h) << 16);
}

// fire-and-forget global->LDS DMA: per-lane global src, LDS dest = wave-uniform
// base + lane*16 (linear)
__device__ __forceinline__ void gload_lds16(const float* g, float* lds) {
    __builtin_amdgcn_global_load_lds(
        (const __attribute__((address_space(1))) unsigned int*)g,
        (__attribute__((address_space(3))) unsigned int*)lds,
        16, 0, 0);
}

// ---------------------------------------------------------------------------
// k0: normalize clusters (fp32), split into bf16 hi/lo (RNE), write
// A-fragments in 32x32x16 MFMA lane layout:
//   A[row=m][k] -> clA[chunk][lane][j], lane = m + 32*half, k = chunk*16+8*half+j
// rows 27..31 zero-pad. Also zero the 32 loss slots. grid = 32 x 64.
// ---------------------------------------------------------------------------
__global__ __launch_bounds__(64) void k0_prep(const float* __restrict__ cl,
                                              unsigned short* __restrict__ clAhi,
                                              unsigned short* __restrict__ clAlo,
                                              float* __restrict__ loss_acc) {
    const int n = blockIdx.x;            // A row 0..31
    const int t = threadIdx.x;
    float inv = 0.f;
    if (n < NCL) {
        const float* row = cl + n * CCH;
        float ss = 0.f;
#pragma unroll
        for (int i = 0; i < CCH / 64; ++i) {
            float v = row[i * 64 + t];
            ss = fmaf(v, v, ss);
        }
#pragma unroll
        for (int off = 32; off > 0; off >>= 1)
            ss += __shfl_xor(ss, off, 64);
        inv = 1.0f / fmaxf(sqrtf(ss), EPSN);
    }
    const int chunk = t >> 1;
    const int half  = t & 1;
    const int lane  = n + 32 * half;
    const size_t base = ((size_t)chunk * 64 + lane) * 8;
#pragma unroll
    for (int j = 0; j < 8; ++j) {
        const int k = chunk * 16 + 8 * half + j;
        float v = (n < NCL) ? cl[n * CCH + k] * inv : 0.f;
        unsigned short h = f2bf(v);
        float lo = v - bf2f(h);
        clAhi[base + j] = h;
        clAlo[base + j] = f2bf(lo);
    }
    if (n == 0 && t < 32) loss_acc[t * 32] = 0.f;   // 32 line-padded slots
}

// ---------------------------------------------------------------------------
// k1: MFMA + global_load_lds staged x (r13 structure — proven 68.6 us best).
//  Block = 256 thr = 4 waves = 128 px; wave w owns the 32-px MFMA tile
//  [px0+32w, px0+32w+32). x chunk [16ch][128px] (8 KB) double-buffered in
//  LDS; per chunk each wave issues 2x 1KB glds (channels 4w..4w+3), one
//  barrier per chunk -> 8 KB/block permanently in flight (36 KB/CU >> the
//  9.2 KB Little's-law need) with NO register-destined x loads to stall on.
//  A-frag dwordx4 loads issued BEFORE the glds so their vmcnt wait doesn't
//  drain the staging pipeline. LDS reads: 32 consecutive floats/half-wave
//  -> 2 lanes/bank = conflict-free.
//  Per chunk: truncation hi/lo split (shift+or, SDWA-foldable), 3 MFMAs
//  (ah*bh + al*bh + ah*bl ~= fp32). C: col=lane&31=pixel,
//  row=(r&3)+8*(r>>2)+4*half; valid rows<27 (r<12 always, r=12..14 half 0).
//  [FINAL ledger — all alternatives measured and reverted:
//   r5 LDS-broadcast clusters +46us (LDS-pipe serialization)
//   r9 unroll4+launch_bounds +7us (spills)
//   r10 per-block __threadfence +210us (buffer_wbl2 flood)
//   r11 v_perm packing +5.5us (kills SDWA folding)
//   r14 barrier-free no-wait: RACE (DMA->ds_read dep invisible to compiler)
//   r15 barrier-free counted vmcnt(4)+asm clobbers +16us (order-pinning
//       defeats scheduler; 4-op budget self-draining) — the per-chunk
//       barrier drain is structural at HIP level (m97 ~20% stall).]
// ---------------------------------------------------------------------------
__global__ __launch_bounds__(256) void k1_main(const float* __restrict__ x,
                                               const unsigned short* __restrict__ clAhi,
                                               const unsigned short* __restrict__ clAlo,
                                               const float* __restrict__ alpha_p,
                                               float* __restrict__ out,
                                               float* __restrict__ loss_acc) {
    __shared__ float xt[2][16][PXT];              // 16 KB

    const int tid  = threadIdx.x;
    const int l    = tid & 63;
    const int w    = tid >> 6;                    // wave 0..3
    const int px0  = blockIdx.x * PXT;
    const int b    = px0 / HWPX;                  // uniform (128 | 9216)
    const int hw0  = px0 - b * HWPX;
    const int col  = l & 31;                      // pixel within wave tile
    const int half = l >> 5;                      // k-half

    // staging source: wave w stages channels 4w+2q+(l>>5), pixels (l&31)*4..+3
    const float* xsrc = x + ((size_t)b * CCH + 4 * w + (l >> 5)) * HWPX
                          + hw0 + (l & 31) * 4;
    const unsigned short* pAh = clAhi + (size_t)l * 8;
    const unsigned short* pAl = clAlo + (size_t)l * 8;

#define STAGE(tc, bf)                                                         \
    {                                                                         \
        gload_lds16(xsrc + ((size_t)(tc) * 16 + 0) * HWPX, &xt[bf][4 * w][0]);\
        gload_lds16(xsrc + ((size_t)(tc) * 16 + 2) * HWPX, &xt[bf][4 * w + 2][0]);\
    }

    f32x16 acc = {0.f, 0.f, 0.f, 0.f, 0.f, 0.f, 0.f, 0.f,
                  0.f, 0.f, 0.f, 0.f, 0.f, 0.f, 0.f, 0.f};
    float ss = 0.f;

    STAGE(0, 0);
    __syncthreads();

    int buf = 0;
#pragma unroll 2
    for (int t = 0; t < NCHK; ++t) {
        // A-fragments FIRST (their vmcnt wait then leaves the glds in flight)
        short8 ah = *(const short8*)(pAh + (size_t)t * 512);   // dwordx4, L2-hit
        short8 al = *(const short8*)(pAl + (size_t)t * 512);

        if (t + 1 < NCHK) STAGE(t + 1, buf ^ 1);  // fire-and-forget next chunk

        float xv[8];
#pragma unroll
        for (int j = 0; j < 8; ++j)
            xv[j] = xt[buf][8 * half + j][32 * w + col];   // conflict-free

        unsigned hb[8], ub[8], lb[8];
#pragma unroll
        for (int j = 0; j < 8; ++j) {
            ss = fmaf(xv[j], xv[j], ss);               // exact fp32 self-norm
            ub[j] = __float_as_uint(xv[j]);
            hb[j] = ub[j] & 0xFFFF0000u;               // truncated bf16 (f32 bits)
            lb[j] = __float_as_uint(xv[j] - __uint_as_float(hb[j]));  // exact lo
        }
        unsigned bhp[4], blp[4];
#pragma unroll
        for (int i = 0; i < 4; ++i) {
            bhp[i] = (ub[2 * i] >> 16) | hb[2 * i + 1];
            blp[i] = (lb[2 * i] >> 16) | (lb[2 * i + 1] & 0xFFFF0000u);
        }
        short8 bh, bl;
#pragma unroll
        for (int i = 0; i < 4; ++i) {
            bh[2 * i]     = (short)(bhp[i] & 0xFFFFu);
            bh[2 * i + 1] = (short)(bhp[i] >> 16);
            bl[2 * i]     = (short)(blp[i] & 0xFFFFu);
            bl[2 * i + 1] = (short)(blp[i] >> 16);
        }

        acc = __builtin_amdgcn_mfma_f32_32x32x16_bf16(ah, bh, acc, 0, 0, 0);
        acc = __builtin_amdgcn_mfma_f32_32x32x16_bf16(al, bh, acc, 0, 0, 0);
        acc = __builtin_amdgcn_mfma_f32_32x32x16_bf16(ah, bl, acc, 0, 0, 0);

        __syncthreads();                          // glds(t+1) landed; readers done
        buf ^= 1;
    }
#undef STAGE

    // ---- epilogue (per wave, identical to r8) ----
    ss += __shfl_xor(ss, 32, 64);                 // combine k-halves of pixel
    const float inv_x = 1.0f / fmaxf(sqrtf(ss), EPSN);
    const float alpha = alpha_p[0];

    float ip[16], ex[16];
#pragma unroll
    for (int r = 0; r < 16; ++r) {
        ip[r] = acc[r] * inv_x;                   // cosine (cl-norm folded in A)
        ex[r] = ip[r] * alpha;
    }

    // valid (row<27): r<12 always; r in 12..14 only on half 0
    float m = -1e30f;
#pragma unroll
    for (int r = 0; r < 12; ++r) m = fmaxf(m, ex[r]);
    if (half == 0) {
#pragma unroll
        for (int r = 12; r < 15; ++r) m = fmaxf(m, ex[r]);
    }
    m = fmaxf(m, __shfl_xor(m, 32, 64));          // max over all 27

    float sum = 0.f;
#pragma unroll
    for (int r = 0; r < 12; ++r) {
        ex[r] = __expf(ex[r] - m);
        sum += ex[r];
    }
#pragma unroll
    for (int r = 12; r < 16; ++r) {
        float e = (half == 0 && r < 15) ? __expf(ex[r] - m) : 0.f;
        ex[r] = e;
        sum += e;
    }
    sum += __shfl_xor(sum, 32, 64);               // denom over all 27
    const float inv_sum = 1.0f / sum;

    float lterm = 0.f;
    float* ob = out + 1 + (size_t)b * (NCL * HWPX) + hw0 + 32 * w + col;
#pragma unroll
    for (int r = 0; r < 16; ++r) {
        const int row = (r & 3) + 8 * (r >> 2) + 4 * half;
        if (r < 12 || (half == 0 && r < 15)) {    // row < 27 only
            float pr = ex[r] * inv_sum;
            ob[(size_t)row * HWPX] = pr;          // coalesced 128B segments
            lterm = fmaf(pr, ip[r], lterm);
        }
    }

    // per-(pixel,half) partials; 64-lane sum counts each (pixel,row) once
#pragma unroll
    for (int off = 32; off > 0; off >>= 1)
        lterm += __shfl_xor(lterm, off, 64);
    if (l == 0)
        atomicAdd(&loss_acc[((blockIdx.x & 7) * 4 + w) * 32], lterm);
}

// ---------------------------------------------------------------------------
// k2: finalize loss (sum the 32 slots)
// ---------------------------------------------------------------------------
__global__ void k2_fin(const float* __restrict__ loss_acc,
                       float* __restrict__ out) {
    float s = 0.f;
#pragma unroll
    for (int i = 0; i < 32; ++i) s += loss_acc[i * 32];
    out[0] = -s * (1.0f / (float)NPIX);
}

extern "C" void kernel_launch(void* const* d_in, const int* in_sizes, int n_in,
                              void* d_out, int out_size, void* d_ws, size_t ws_size,
                              hipStream_t stream) {
    const float* x     = (const float*)d_in[0];
    const float* cl    = (const float*)d_in[1];
    const float* alpha = (const float*)d_in[2];
    float* out = (float*)d_out;

    float*          loss_acc = (float*)d_ws;                       // 32 slots x 128B
    unsigned short* clAhi    = (unsigned short*)((char*)d_ws + 4096);
    unsigned short* clAlo    = clAhi + 32 * 64 * 8;                // +32KB

    hipLaunchKernelGGL(k0_prep, dim3(32), dim3(64), 0, stream,
                       cl, clAhi, clAlo, loss_acc);
    hipLaunchKernelGGL(k1_main, dim3(NPIX / PXT), dim3(256), 0, stream,
                       x, clAhi, clAlo, alpha, out, loss_acc);
    hipLaunchKernelGGL(k2_fin, dim3(1), dim3(1), 0, stream, loss_acc, out);
}